// Round 1
// baseline (2510.034 us; speedup 1.0000x reference)
//
#include <hip/hip_runtime.h>
#include <hip/hip_bf16.h>
#include <stdint.h>

// SAGE (GraphSAGE, LSTM aggregator). f32 I/O, bf16 MFMA internally.
// N=30000, DMAX=16, dims 128 -> 256 -> 64.
// R7 -> R8 (R7: 1601us; rec2 1217us, FETCH 2.67GB @2.4TB/s == dispatch time ->
// fetch-path bound. Accounting: xg2 gathers 983MB (2048B/row x 64rows x 16steps
// x 469blk = whole 61MB table re-streamed EVERY step) + ~1.6GB Whh2 L2-miss
// refetch (512KB weights thrashed out of 4MB/XCD L2 by the 8MB/step gather
// stream)):
//   1. KILL the xg tables. Fuse x@Wih^T into the recurrence: gather raw
//      neighbor rows (h1: 512B, bf16-feat: 256B) straight into MFMA A-frags
//      (lane(q,m16) loads 16B @ row(m16)*F + kk*32 + q*8), accumulate
//      gates = x@Wih^T + h@Whh^T + bih + bhh in f32. Gather footprint 4x
//      smaller -> stream 2MB/step/XCD < L2 -> weights stay resident.
//      MFMA work doubles (503 GFLOP rec2 ~ 61us pipe time; util was 8.5%).
//   2. xg_gemm dispatches deleted; tiny cvt_feat (feat->bf16, same rounding
//      stage_tile used, so layer-1 products identical) replaces them.
//   3. Biases now f32-accumulated (old path rounded x@Wih+b to bf16 first) ->
//      numerics move TOWARD reference.
// Verified layouts (learn_hip m89/m91): A[m=lane&15][k=q*8+j],
// D[row=q*4+r][col=lane&15]; W[4F,F] row-major == gemm-BT B-frag layout.

#define NN 30000
#define DMAXX 16

typedef __bf16 bf16_t;
typedef __bf16 bf16x8 __attribute__((ext_vector_type(8)));
typedef float f32x4 __attribute__((ext_vector_type(4)));

// persistent scratch (fully rewritten every call; no cross-call state reuse)
__device__ __align__(16) bf16_t g_hbuf[(size_t)NN * 256];    // layer-1 output h1
__device__ __align__(16) bf16_t g_fbuf[(size_t)NN * 128];    // bf16 copy of feat
__device__ __align__(16) bf16_t g_wbuf[753664];              // bf16 weight copies

#define OFF_WIH1 0
#define OFF_WHH1 65536
#define OFF_WSELF1 131072
#define OFF_WNEIGH1 163840
#define OFF_WIH2 196608
#define OFF_WHH2 458752
#define OFF_WSELF2 720896
#define OFF_WNEIGH2 737280
#define W_TOTAL 753664

__global__ __launch_bounds__(256)
void cvt_weights(const float* __restrict__ s0, const float* __restrict__ s1,
                 const float* __restrict__ s2, const float* __restrict__ s3,
                 const float* __restrict__ s4, const float* __restrict__ s5,
                 const float* __restrict__ s6, const float* __restrict__ s7)
{
    int i = (blockIdx.x * 256 + threadIdx.x) * 4;
    if (i >= W_TOTAL) return;
    const float* src; int off;
    if      (i < OFF_WHH1)   { src = s0; off = OFF_WIH1; }
    else if (i < OFF_WSELF1) { src = s1; off = OFF_WHH1; }
    else if (i < OFF_WNEIGH1){ src = s2; off = OFF_WSELF1; }
    else if (i < OFF_WIH2)   { src = s3; off = OFF_WNEIGH1; }
    else if (i < OFF_WHH2)   { src = s4; off = OFF_WIH2; }
    else if (i < OFF_WSELF2) { src = s5; off = OFF_WHH2; }
    else if (i < OFF_WNEIGH2){ src = s6; off = OFF_WSELF2; }
    else                     { src = s7; off = OFF_WNEIGH2; }
    float4 v = *reinterpret_cast<const float4*>(src + (i - off));
    bf16_t o[4] __attribute__((aligned(8)));
    o[0] = (bf16_t)v.x; o[1] = (bf16_t)v.y; o[2] = (bf16_t)v.z; o[3] = (bf16_t)v.w;
    *reinterpret_cast<uint2*>(&g_wbuf[i]) = *reinterpret_cast<const uint2*>(o);
}

// feat f32 -> bf16 table (identical rounding to the old stage_tile XF32 path)
__global__ __launch_bounds__(256)
void cvt_feat(const float* __restrict__ src, bf16_t* __restrict__ dst)
{
    int i = (blockIdx.x * 256 + threadIdx.x) * 8;   // grid covers NN*128 exactly
    float4 f0 = *reinterpret_cast<const float4*>(src + i);
    float4 f1 = *reinterpret_cast<const float4*>(src + i + 4);
    bf16_t t[8] __attribute__((aligned(16)));
    t[0]=(bf16_t)f0.x; t[1]=(bf16_t)f0.y; t[2]=(bf16_t)f0.z; t[3]=(bf16_t)f0.w;
    t[4]=(bf16_t)f1.x; t[5]=(bf16_t)f1.y; t[6]=(bf16_t)f1.z; t[7]=(bf16_t)f1.w;
    *reinterpret_cast<uint4*>(&dst[i]) = *reinterpret_cast<const uint4*>(t);
}

__device__ __forceinline__ float fsig(float x) { return 1.0f / (1.0f + __expf(-x)); }
__device__ __forceinline__ float ftanh(float x) { return 1.0f - 2.0f / (__expf(2.0f * x) + 1.0f); }

// stage a 64-row bf16 x-tile (global, row-clamped) into LDS
template<int F, int LDA, int NT>
__device__ __forceinline__ void stage_tile(bf16_t* dst, const bf16_t* src, int row0, int tid)
{
    constexpr int UN = F / 8;          // 16B units per row
    for (int e = tid; e < 64 * UN; e += NT) {
        int m = e / UN, sub = e - m * UN;
        int row = row0 + m; if (row >= NN) row = NN - 1;
        const bf16_t* p = src + (size_t)row * F + sub * 8;
        *reinterpret_cast<uint4*>(&dst[m * LDA + sub * 8]) = *reinterpret_cast<const uint4*>(p);
    }
}

// LSTM recurrence over gathered neighbors + fused fc epilogue.
// gates = x_nbr @ Wih^T + h @ Whh^T + bih + bhh  (x_nbr gathered per step,
// straight into MFMA A-frags; no precomputed xg table)
// out = x_self@Wself^T + h_fin@Wneigh^T + bout
template<int F, int NW, int OUTF, bool RELU, typename OutT>
__global__ __launch_bounds__(NW * 64, 2)
void sage_rec(const bf16_t* __restrict__ xtab,   // [NN,F] bf16: gather + self rows
              const int* __restrict__ nbr_idx, const int* __restrict__ deg,
              const bf16_t* __restrict__ Wih, const bf16_t* __restrict__ Whh,
              const float* __restrict__ bih, const float* __restrict__ bhh,
              const bf16_t* __restrict__ Wself, const bf16_t* __restrict__ Wneigh,
              const float* __restrict__ bout, OutT* __restrict__ outp)
{
    constexpr int M = 64, RT = 4, LDA = F + 8, KK = F / 32, NT = NW * 64;
    constexpr int CPW = F / NW, CT = CPW / 16;
    static_assert(CPW % 16 == 0, "");
    static_assert((DMAXX & 1) == 0, "final h must land in buf[0]");
    const int tid = threadIdx.x, wave = tid >> 6, lane = tid & 63;
    const int q = lane >> 4, m16 = lane & 15;
    const int node0 = blockIdx.x * M;

    __shared__ __align__(16) bf16_t s_h[2][M * LDA];   // double-buffered h
    __shared__ int s_idx[M * DMAXX];
    __shared__ int s_deg[M];

    for (int i = tid; i < M * DMAXX; i += NT) {
        int m = i >> 4;
        int node = node0 + m; if (node >= NN) node = NN - 1;
        int v = nbr_idx[node * DMAXX + (i & 15)];
        if (v < 0) v = 0; if (v >= NN) v = NN - 1;
        s_idx[i] = v;
    }
    for (int i = tid; i < M; i += NT) {
        int node = node0 + i; if (node >= NN) node = NN - 1;
        s_deg[i] = deg[node];
    }
    for (int i = tid; i < M * LDA; i += NT) s_h[0][i] = (bf16_t)0.0f;
    __syncthreads();

    int dg[RT][4];
    #pragma unroll
    for (int rt = 0; rt < RT; ++rt)
        #pragma unroll
        for (int r = 0; r < 4; ++r)
            dg[rt][r] = s_deg[rt * 16 + q * 4 + r];

    // gate bias (bih+bhh), per (ct,g); col = g*F + wave*CPW + ct*16 + m16
    float bias[CT][4];
    #pragma unroll
    for (int ct = 0; ct < CT; ++ct)
        #pragma unroll
        for (int g = 0; g < 4; ++g) {
            int col = g * F + wave * CPW + ct * 16 + m16;
            bias[ct][g] = bih[col] + bhh[col];
        }

    f32x4 c_[RT][CT];
    #pragma unroll
    for (int rt = 0; rt < RT; ++rt)
        #pragma unroll
        for (int ct = 0; ct < CT; ++ct)
            #pragma unroll
            for (int r = 0; r < 4; ++r) c_[rt][ct][r] = 0.0f;

    #pragma unroll 1
    for (int t = 0; t < DMAXX; ++t) {
        const bf16_t* cur = s_h[t & 1];
        bf16_t* nxt = s_h[(t + 1) & 1];
        // A-frag gather rows for this step: tile-row m16 of each rt group
        int arow[RT];
        #pragma unroll
        for (int rt = 0; rt < RT; ++rt)
            arow[rt] = s_idx[(rt * 16 + m16) * DMAXX + t];

        #pragma unroll
        for (int ct = 0; ct < CT; ++ct) {
            const int wc = wave * CPW + ct * 16 + m16;
            f32x4 acc[RT][4];
            #pragma unroll
            for (int rt = 0; rt < RT; ++rt)
                #pragma unroll
                for (int g = 0; g < 4; ++g)
                    #pragma unroll
                    for (int r = 0; r < 4; ++r) acc[rt][g][r] = bias[ct][g];

            // 1-deep pipeline on the gathered x A-frags
            bf16x8 ax[RT];
            #pragma unroll
            for (int rt = 0; rt < RT; ++rt)
                ax[rt] = *reinterpret_cast<const bf16x8*>(xtab + (size_t)arow[rt] * F + q * 8);

            #pragma unroll
            for (int kk = 0; kk < KK; ++kk) {
                const int ko = kk * 32 + q * 8;
                bf16x8 ah[RT];
                #pragma unroll
                for (int rt = 0; rt < RT; ++rt)
                    ah[rt] = *reinterpret_cast<const bf16x8*>(&cur[(rt * 16 + m16) * LDA + ko]);
                bf16x8 axn[RT];
                if (kk + 1 < KK) {
                    #pragma unroll
                    for (int rt = 0; rt < RT; ++rt)
                        axn[rt] = *reinterpret_cast<const bf16x8*>(xtab + (size_t)arow[rt] * F + ko + 32);
                }
                #pragma unroll
                for (int g = 0; g < 4; ++g) {
                    bf16x8 bi = *reinterpret_cast<const bf16x8*>(Wih + (size_t)(g * F + wc) * F + ko);
                    bf16x8 bh = *reinterpret_cast<const bf16x8*>(Whh + (size_t)(g * F + wc) * F + ko);
                    #pragma unroll
                    for (int rt = 0; rt < RT; ++rt) {
                        acc[rt][g] = __builtin_amdgcn_mfma_f32_16x16x32_bf16(ax[rt], bi, acc[rt][g], 0, 0, 0);
                        acc[rt][g] = __builtin_amdgcn_mfma_f32_16x16x32_bf16(ah[rt], bh, acc[rt][g], 0, 0, 0);
                    }
                }
                if (kk + 1 < KK) {
                    #pragma unroll
                    for (int rt = 0; rt < RT; ++rt) ax[rt] = axn[rt];
                }
            }

            // pointwise LSTM update + masked store:
            //   t <  deg : write h_new (and update c)
            //   t == deg : copy frozen h from cur (this thread's t-1 write)
            //   t >  deg : skip -- nxt already holds the frozen value
            #pragma unroll
            for (int rt = 0; rt < RT; ++rt)
                #pragma unroll
                for (int r = 0; r < 4; ++r) {
                    float iv = fsig (acc[rt][0][r]);
                    float fv = fsig (acc[rt][1][r]);
                    float gv = ftanh(acc[rt][2][r]);
                    float ov = fsig (acc[rt][3][r]);
                    float cn = fv * c_[rt][ct][r] + iv * gv;
                    float hv = ov * ftanh(cn);
                    const int pos = (rt * 16 + q * 4 + r) * LDA + wave * CPW + ct * 16 + m16;
                    int d = dg[rt][r];
                    if (t < d) {
                        c_[rt][ct][r] = cn;
                        nxt[pos] = (bf16_t)hv;
                    } else if (t == d) {
                        reinterpret_cast<unsigned short*>(nxt)[pos] =
                            reinterpret_cast<const unsigned short*>(cur)[pos];
                    }
                }
        }
        __syncthreads();   // nxt fully written; cur fully consumed
    }

    // final h is in s_h[0]; stage self-rows into retired s_h[1] for epilogue
    stage_tile<F, LDA, NT>(s_h[1], xtab, node0, tid);
    __syncthreads();

    // epilogue: out = x_self @ Wself^T + h_fin @ Wneigh^T + bout (+relu)
    constexpr int NCT = OUTF / 16;
    constexpr int TILES = NCT * RT;
    constexpr int TPW = TILES / NW;
    static_assert(TILES % NW == 0, "");
    #pragma unroll
    for (int tt = 0; tt < TPW; ++tt) {
        int tile = wave * TPW + tt;
        int ot = tile % NCT, rt = tile / NCT;
        f32x4 o;
        o[0] = 0.f; o[1] = 0.f; o[2] = 0.f; o[3] = 0.f;
        #pragma unroll
        for (int kk = 0; kk < KK; ++kk) {
            const int ko = kk * 32 + q * 8;
            bf16x8 axs = *reinterpret_cast<const bf16x8*>(&s_h[1][(rt * 16 + m16) * LDA + ko]);
            bf16x8 am  = *reinterpret_cast<const bf16x8*>(&s_h[0][(rt * 16 + m16) * LDA + ko]);
            bf16x8 bs = *reinterpret_cast<const bf16x8*>(Wself  + (size_t)(ot * 16 + m16) * F + ko);
            bf16x8 bn = *reinterpret_cast<const bf16x8*>(Wneigh + (size_t)(ot * 16 + m16) * F + ko);
            o = __builtin_amdgcn_mfma_f32_16x16x32_bf16(axs, bs, o, 0, 0, 0);
            o = __builtin_amdgcn_mfma_f32_16x16x32_bf16(am,  bn, o, 0, 0, 0);
        }
        int ocol = ot * 16 + m16;
        float bias2 = bout[ocol];
        #pragma unroll
        for (int r = 0; r < 4; ++r) {
            int node = node0 + rt * 16 + q * 4 + r;
            if (node < NN) {
                float v = o[r] + bias2;
                if (RELU) v = fmaxf(v, 0.0f);
                outp[(size_t)node * OUTF + ocol] = (OutT)v;
            }
        }
    }
}

extern "C" void kernel_launch(void* const* d_in, const int* in_sizes, int n_in,
                              void* d_out, int out_size, void* d_ws, size_t ws_size,
                              hipStream_t stream)
{
    const float* feat    = (const float*)d_in[0];
    const int*   nbr     = (const int*)d_in[1];
    const int*   degp    = (const int*)d_in[2];
    const float* Wih1    = (const float*)d_in[3];
    const float* Whh1    = (const float*)d_in[4];
    const float* bih1    = (const float*)d_in[5];
    const float* bhh1    = (const float*)d_in[6];
    const float* Wself1  = (const float*)d_in[7];
    const float* Wneigh1 = (const float*)d_in[8];
    const float* b1      = (const float*)d_in[9];
    const float* Wih2    = (const float*)d_in[10];
    const float* Whh2    = (const float*)d_in[11];
    const float* bih2    = (const float*)d_in[12];
    const float* bhh2    = (const float*)d_in[13];
    const float* Wself2  = (const float*)d_in[14];
    const float* Wneigh2 = (const float*)d_in[15];
    const float* b2      = (const float*)d_in[16];

    bf16_t *hglob, *wglob, *fglob;
    hipGetSymbolAddress((void**)&hglob, HIP_SYMBOL(g_hbuf));
    hipGetSymbolAddress((void**)&wglob, HIP_SYMBOL(g_wbuf));
    hipGetSymbolAddress((void**)&fglob, HIP_SYMBOL(g_fbuf));

    cvt_weights<<<W_TOTAL / 4 / 256, 256, 0, stream>>>(
        Wih1, Whh1, Wself1, Wneigh1, Wih2, Whh2, Wself2, Wneigh2);

    cvt_feat<<<NN * 128 / 8 / 256, 256, 0, stream>>>(feat, fglob);

    const int grid = (NN + 63) / 64;   // 469 WGs

    sage_rec<128, 8, 256, true, bf16_t><<<grid, 512, 0, stream>>>(
        fglob, nbr, degp,
        wglob + OFF_WIH1, wglob + OFF_WHH1, bih1, bhh1,
        wglob + OFF_WSELF1, wglob + OFF_WNEIGH1, b1, hglob);

    sage_rec<256, 8, 64, false, float><<<grid, 512, 0, stream>>>(
        hglob, nbr, degp,
        wglob + OFF_WIH2, wglob + OFF_WHH2, bih2, bhh2,
        wglob + OFF_WSELF2, wglob + OFF_WNEIGH2, b2, (float*)d_out);
}

// Round 2
// 1243.445 us; speedup vs baseline: 2.0186x; 2.0186x over previous
//
#include <hip/hip_runtime.h>
#include <hip/hip_bf16.h>
#include <stdint.h>

// SAGE (GraphSAGE, LSTM aggregator). f32 I/O, bf16 MFMA internally.
// N=30000, DMAX=16, dims 128 -> 256 -> 64.
// R8 -> R9 (R8 FAILED 2510us: fusing x@Wih into the recurrence re-did that
// GEMM per (node,step) = 16x the FLOPs, and the per-lane 16-row scattered
// A-gathers x 8 waves x 2 ct hit L2 at ~0% -- FETCH 3.85GB == bytes issued.
// REVERT to R7 xg-precompute structure (proven 1601us) and attack its real
// cost scale: all rec work (983MB unique gather + ~1.6GB weight re-stream +
// FLOPs) scales with steps run = 16, but avg deg = 8.5 -> ~47% masked-dead):
//   1. build_perm: counting-sort node ids by degree (16 bins, one block,
//      ~20us). Blocks get uniform-degree nodes; rec loops to tmax =
//      max(deg in block) ~= bucket degree. Work ratio ~8.7/16 = 0.55 on
//      gathers, weights, MFMA. Per-node results bit-identical (MFMA rows
//      independent); outputs scattered to original node rows.
//   2. Final h lands in s_h[tmax&1] (variable parity) -> epilogue uses
//      hfin/hstage pointers instead of fixed buffers.
// Verified layouts (learn_hip m89/m91): A[m=lane&15][k=q*8+j],
// D[row=q*4+r][col=lane&15]; W[4F,F] row-major == gemm-BT B-frag layout.

#define NN 30000
#define DMAXX 16

typedef __bf16 bf16_t;
typedef __bf16 bf16x8 __attribute__((ext_vector_type(8)));
typedef float f32x4 __attribute__((ext_vector_type(4)));
typedef unsigned short u16x4 __attribute__((ext_vector_type(4)));

// persistent scratch (fully rewritten every call; no cross-call state reuse)
__device__ __align__(16) bf16_t g_hbuf[(size_t)NN * 256];    // layer-1 output h1
__device__ __align__(16) bf16_t g_xg1[(size_t)NN * 512];     // feat@Wih1^T + biases
__device__ __align__(16) bf16_t g_xg2[(size_t)NN * 1024];    // h1@Wih2^T + biases
__device__ __align__(16) bf16_t g_wbuf[753664];              // bf16 weight copies
__device__ int g_perm[NN];                                   // degree-sorted node ids

#define OFF_WIH1 0
#define OFF_WHH1 65536
#define OFF_WSELF1 131072
#define OFF_WNEIGH1 163840
#define OFF_WIH2 196608
#define OFF_WHH2 458752
#define OFF_WSELF2 720896
#define OFF_WNEIGH2 737280
#define W_TOTAL 753664

__global__ __launch_bounds__(256)
void cvt_weights(const float* __restrict__ s0, const float* __restrict__ s1,
                 const float* __restrict__ s2, const float* __restrict__ s3,
                 const float* __restrict__ s4, const float* __restrict__ s5,
                 const float* __restrict__ s6, const float* __restrict__ s7)
{
    int i = (blockIdx.x * 256 + threadIdx.x) * 4;
    if (i >= W_TOTAL) return;
    const float* src; int off;
    if      (i < OFF_WHH1)   { src = s0; off = OFF_WIH1; }
    else if (i < OFF_WSELF1) { src = s1; off = OFF_WHH1; }
    else if (i < OFF_WNEIGH1){ src = s2; off = OFF_WSELF1; }
    else if (i < OFF_WIH2)   { src = s3; off = OFF_WNEIGH1; }
    else if (i < OFF_WHH2)   { src = s4; off = OFF_WIH2; }
    else if (i < OFF_WSELF2) { src = s5; off = OFF_WHH2; }
    else if (i < OFF_WNEIGH2){ src = s6; off = OFF_WSELF2; }
    else                     { src = s7; off = OFF_WNEIGH2; }
    float4 v = *reinterpret_cast<const float4*>(src + (i - off));
    bf16_t o[4] __attribute__((aligned(8)));
    o[0] = (bf16_t)v.x; o[1] = (bf16_t)v.y; o[2] = (bf16_t)v.z; o[3] = (bf16_t)v.w;
    *reinterpret_cast<uint2*>(&g_wbuf[i]) = *reinterpret_cast<const uint2*>(o);
}

// counting sort of node ids by degree (deg in 1..DMAXX). One block.
// Non-stable (atomic slot grab) -- per-node results are independent of
// grouping, so any permutation is correct.
__global__ __launch_bounds__(256)
void build_perm(const int* __restrict__ deg, int* __restrict__ perm)
{
    __shared__ int s_base[DMAXX + 1];
    const int tid = threadIdx.x;
    if (tid <= DMAXX) s_base[tid] = 0;
    __syncthreads();
    for (int i = tid; i < NN; i += 256) {
        int d = deg[i]; d = d < 0 ? 0 : (d > DMAXX ? DMAXX : d);
        atomicAdd(&s_base[d], 1);
    }
    __syncthreads();
    if (tid == 0) {
        int acc = 0;
        for (int d = 0; d <= DMAXX; ++d) { int c = s_base[d]; s_base[d] = acc; acc += c; }
    }
    __syncthreads();
    for (int i = tid; i < NN; i += 256) {
        int d = deg[i]; d = d < 0 ? 0 : (d > DMAXX ? DMAXX : d);
        int p = atomicAdd(&s_base[d], 1);
        perm[p] = i;
    }
}

__device__ __forceinline__ float fsig(float x) { return 1.0f / (1.0f + __expf(-x)); }
__device__ __forceinline__ float ftanh(float x) { return 1.0f - 2.0f / (__expf(2.0f * x) + 1.0f); }
__device__ __forceinline__ float bf2f(unsigned short s) {
    union { unsigned u; float f; } v; v.u = ((unsigned)s) << 16; return v.f;
}

// stage a 64-row x-tile (linear rows, row-clamped) into LDS as bf16
template<int F, int LDA, int NT, bool XF32>
__device__ __forceinline__ void stage_tile(bf16_t* dst, const void* src, int row0, int tid)
{
    constexpr int UN = F / 8;          // 16B(bf16) units per row
    for (int e = tid; e < 64 * UN; e += NT) {
        int m = e / UN, sub = e - m * UN;
        int row = row0 + m; if (row >= NN) row = NN - 1;
        if constexpr (XF32) {
            const float* p = (const float*)src + (size_t)row * F + sub * 8;
            float4 f0 = reinterpret_cast<const float4*>(p)[0];
            float4 f1 = reinterpret_cast<const float4*>(p)[1];
            bf16_t t[8] __attribute__((aligned(16)));
            t[0]=(bf16_t)f0.x; t[1]=(bf16_t)f0.y; t[2]=(bf16_t)f0.z; t[3]=(bf16_t)f0.w;
            t[4]=(bf16_t)f1.x; t[5]=(bf16_t)f1.y; t[6]=(bf16_t)f1.z; t[7]=(bf16_t)f1.w;
            *reinterpret_cast<uint4*>(&dst[m * LDA + sub * 8]) = *reinterpret_cast<const uint4*>(t);
        } else {
            const bf16_t* p = (const bf16_t*)src + (size_t)row * F + sub * 8;
            *reinterpret_cast<uint4*>(&dst[m * LDA + sub * 8]) = *reinterpret_cast<const uint4*>(p);
        }
    }
}

// stage a 64-row x-tile with per-row node ids (from LDS array) into LDS
template<int F, int LDA, int NT, bool XF32>
__device__ __forceinline__ void stage_rows(bf16_t* dst, const void* src, const int* nodes, int tid)
{
    constexpr int UN = F / 8;
    for (int e = tid; e < 64 * UN; e += NT) {
        int m = e / UN, sub = e - m * UN;
        int row = nodes[m];
        if constexpr (XF32) {
            const float* p = (const float*)src + (size_t)row * F + sub * 8;
            float4 f0 = reinterpret_cast<const float4*>(p)[0];
            float4 f1 = reinterpret_cast<const float4*>(p)[1];
            bf16_t t[8] __attribute__((aligned(16)));
            t[0]=(bf16_t)f0.x; t[1]=(bf16_t)f0.y; t[2]=(bf16_t)f0.z; t[3]=(bf16_t)f0.w;
            t[4]=(bf16_t)f1.x; t[5]=(bf16_t)f1.y; t[6]=(bf16_t)f1.z; t[7]=(bf16_t)f1.w;
            *reinterpret_cast<uint4*>(&dst[m * LDA + sub * 8]) = *reinterpret_cast<const uint4*>(t);
        } else {
            const bf16_t* p = (const bf16_t*)src + (size_t)row * F + sub * 8;
            *reinterpret_cast<uint4*>(&dst[m * LDA + sub * 8]) = *reinterpret_cast<const uint4*>(p);
        }
    }
}

// xg[N, 4F] (gate-interleaved [c][g]) = x[N,F] @ W[4F,F]^T + b0 + b1
template<int F, int G, int NW, bool XF32>
__global__ __launch_bounds__(NW * 64, 2)
void xg_gemm(const void* __restrict__ xsrc_v, const bf16_t* __restrict__ W,
             const float* __restrict__ b0, const float* __restrict__ b1v,
             bf16_t* __restrict__ xg)
{
    constexpr int LDA = F + 8, KK = F / 32, NT = NW * 64;
    constexpr int CPW = G / NW;        // linear out-cols per wave
    constexpr int CT = CPW / 16;
    static_assert(CPW % 16 == 0 && F % 16 == 0, "");
    const int tid = threadIdx.x, wave = tid >> 6, lane = tid & 63;
    const int q = lane >> 4, m16 = lane & 15;
    const int row0 = blockIdx.x * 64;

    __shared__ __align__(16) bf16_t s_x[64 * LDA];
    stage_tile<F, LDA, NT, XF32>(s_x, xsrc_v, row0, tid);
    __syncthreads();

    #pragma unroll
    for (int ct = 0; ct < CT; ++ct) {
        const int lc0 = wave * CPW + ct * 16;   // linear col block (within one gate)
        const int g = lc0 / F, c0 = lc0 - g * F;
        const float bias = b0[lc0 + m16] + b1v[lc0 + m16];
        f32x4 acc[4];
        #pragma unroll
        for (int rt = 0; rt < 4; ++rt)
            #pragma unroll
            for (int r = 0; r < 4; ++r) acc[rt][r] = bias;
        #pragma unroll
        for (int kk = 0; kk < KK; ++kk) {
            const int ko = kk * 32 + q * 8;
            bf16x8 b = *reinterpret_cast<const bf16x8*>(W + (size_t)(lc0 + m16) * F + ko);
            #pragma unroll
            for (int rt = 0; rt < 4; ++rt) {
                bf16x8 a = *reinterpret_cast<const bf16x8*>(&s_x[(rt * 16 + m16) * LDA + ko]);
                acc[rt] = __builtin_amdgcn_mfma_f32_16x16x32_bf16(a, b, acc[rt], 0, 0, 0);
            }
        }
        #pragma unroll
        for (int rt = 0; rt < 4; ++rt)
            #pragma unroll
            for (int r = 0; r < 4; ++r) {
                int row = row0 + rt * 16 + q * 4 + r;
                if (row < NN)
                    xg[(size_t)row * G + (size_t)(c0 + m16) * 4 + g] = (bf16_t)acc[rt][r];
            }
    }
}

// LSTM recurrence over gathered neighbors + fused fc epilogue.
// Block b processes nodes perm[b*64 .. b*64+63] (degree-sorted) and loops
// only to tmax = max(deg in block).
// gates = gather(xg) + h @ Whh^T ; out = x_self@Wself^T + h_fin@Wneigh^T + b
template<int F, int NW, int OUTF, bool RELU, bool XF32, typename OutT>
__global__ __launch_bounds__(NW * 64, 2)
void sage_rec(const void* __restrict__ xself_v,
              const bf16_t* __restrict__ xg,
              const int* __restrict__ nbr_idx, const int* __restrict__ deg,
              const int* __restrict__ perm,
              const bf16_t* __restrict__ Whh,
              const bf16_t* __restrict__ Wself, const bf16_t* __restrict__ Wneigh,
              const float* __restrict__ bout, OutT* __restrict__ outp)
{
    constexpr int M = 64, RT = 4, LDA = F + 8, KK = F / 32, NT = NW * 64;
    constexpr int CPW = F / NW, CT = CPW / 16, G4 = 4 * F;
    static_assert(CPW % 16 == 0, "");
    const int tid = threadIdx.x, wave = tid >> 6, lane = tid & 63;
    const int q = lane >> 4, m16 = lane & 15;
    const int slot0 = blockIdx.x * M;

    __shared__ __align__(16) bf16_t s_h[2][M * LDA];   // double-buffered h
    __shared__ int s_idx[M * DMAXX];
    __shared__ int s_deg[M];
    __shared__ int s_node[M];
    __shared__ int s_tmax;

    for (int i = tid; i < M; i += NT) {
        int slot = slot0 + i; if (slot >= NN) slot = NN - 1;
        int node = perm[slot];
        s_node[i] = node;
        s_deg[i] = deg[node];
    }
    __syncthreads();
    for (int i = tid; i < M * DMAXX; i += NT) {
        int node = s_node[i >> 4];
        int v = nbr_idx[node * DMAXX + (i & 15)];
        if (v < 0) v = 0; if (v >= NN) v = NN - 1;
        s_idx[i] = v;
    }
    for (int i = tid; i < M * LDA; i += NT) s_h[0][i] = (bf16_t)0.0f;
    if (tid == 0) {
        int mx = 1;
        for (int i = 0; i < M; ++i) { int d = s_deg[i]; mx = d > mx ? d : mx; }
        s_tmax = mx;
    }
    __syncthreads();
    const int tmax = s_tmax;   // uniform-degree blocks: ~= block's degree bucket

    int dg[RT][4];
    #pragma unroll
    for (int rt = 0; rt < RT; ++rt)
        #pragma unroll
        for (int r = 0; r < 4; ++r)
            dg[rt][r] = s_deg[rt * 16 + q * 4 + r];

    f32x4 c_[RT][CT];
    #pragma unroll
    for (int rt = 0; rt < RT; ++rt)
        #pragma unroll
        for (int ct = 0; ct < CT; ++ct)
            #pragma unroll
            for (int r = 0; r < 4; ++r) c_[rt][ct][r] = 0.0f;

    #pragma unroll 1
    for (int t = 0; t < tmax; ++t) {
        const bf16_t* cur = s_h[t & 1];
        bf16_t* nxt = s_h[(t + 1) & 1];
        #pragma unroll
        for (int ct = 0; ct < CT; ++ct) {
            // gather gate-init (xg = x@Wih^T + biases), 8B/elem, 128B/row/wave
            u16x4 u[RT][4];
            #pragma unroll
            for (int rt = 0; rt < RT; ++rt)
                #pragma unroll
                for (int r = 0; r < 4; ++r) {
                    int row = s_idx[(rt * 16 + q * 4 + r) * DMAXX + t];
                    u[rt][r] = *reinterpret_cast<const u16x4*>(
                        xg + (size_t)row * G4 + (size_t)(wave * CPW + ct * 16 + m16) * 4);
                }
            f32x4 acc[RT][4];
            #pragma unroll
            for (int rt = 0; rt < RT; ++rt)
                #pragma unroll
                for (int g = 0; g < 4; ++g)
                    #pragma unroll
                    for (int r = 0; r < 4; ++r) acc[rt][g][r] = 0.0f;
            #pragma unroll
            for (int kk = 0; kk < KK; ++kk) {
                const int ko = kk * 32 + q * 8;
                bf16x8 ah[RT];
                #pragma unroll
                for (int rt = 0; rt < RT; ++rt)
                    ah[rt] = *reinterpret_cast<const bf16x8*>(&cur[(rt * 16 + m16) * LDA + ko]);
                #pragma unroll
                for (int g = 0; g < 4; ++g) {
                    bf16x8 bh = *reinterpret_cast<const bf16x8*>(
                        Whh + (size_t)(g * F + wave * CPW + ct * 16 + m16) * F + ko);
                    #pragma unroll
                    for (int rt = 0; rt < RT; ++rt)
                        acc[rt][g] = __builtin_amdgcn_mfma_f32_16x16x32_bf16(ah[rt], bh, acc[rt][g], 0, 0, 0);
                }
            }
            // pointwise LSTM update + masked store:
            //   t <  deg : write h_new (and update c)
            //   t == deg : copy frozen h from cur (this thread's t-1 write)
            //   t >  deg : skip -- nxt already holds the frozen value
            #pragma unroll
            for (int rt = 0; rt < RT; ++rt)
                #pragma unroll
                for (int r = 0; r < 4; ++r) {
                    float iv = fsig (acc[rt][0][r] + bf2f(u[rt][r].x));
                    float fv = fsig (acc[rt][1][r] + bf2f(u[rt][r].y));
                    float gv = ftanh(acc[rt][2][r] + bf2f(u[rt][r].z));
                    float ov = fsig (acc[rt][3][r] + bf2f(u[rt][r].w));
                    float cn = fv * c_[rt][ct][r] + iv * gv;
                    float hv = ov * ftanh(cn);
                    const int pos = (rt * 16 + q * 4 + r) * LDA + wave * CPW + ct * 16 + m16;
                    int d = dg[rt][r];
                    if (t < d) {
                        c_[rt][ct][r] = cn;
                        nxt[pos] = (bf16_t)hv;
                    } else if (t == d) {
                        reinterpret_cast<unsigned short*>(nxt)[pos] =
                            reinterpret_cast<const unsigned short*>(cur)[pos];
                    }
                }
        }
        __syncthreads();   // nxt fully written; cur fully consumed
    }

    // final h is in s_h[tmax&1]; stage self-rows into the other buffer
    const int fb = tmax & 1;
    const bf16_t* hfin = s_h[fb];
    bf16_t* hstage = s_h[fb ^ 1];
    stage_rows<F, LDA, NT, XF32>(hstage, xself_v, s_node, tid);
    __syncthreads();

    // epilogue: out = x_self @ Wself^T + h_fin @ Wneigh^T + bout (+relu)
    constexpr int NCT = OUTF / 16;
    constexpr int TILES = NCT * RT;
    constexpr int TPW = TILES / NW;
    static_assert(TILES % NW == 0, "");
    #pragma unroll
    for (int tt = 0; tt < TPW; ++tt) {
        int tile = wave * TPW + tt;
        int ot = tile % NCT, rt = tile / NCT;
        f32x4 o;
        o[0] = 0.f; o[1] = 0.f; o[2] = 0.f; o[3] = 0.f;
        #pragma unroll
        for (int kk = 0; kk < KK; ++kk) {
            const int ko = kk * 32 + q * 8;
            bf16x8 axs = *reinterpret_cast<const bf16x8*>(&hstage[(rt * 16 + m16) * LDA + ko]);
            bf16x8 am  = *reinterpret_cast<const bf16x8*>(&hfin[(rt * 16 + m16) * LDA + ko]);
            bf16x8 bs = *reinterpret_cast<const bf16x8*>(Wself  + (size_t)(ot * 16 + m16) * F + ko);
            bf16x8 bn = *reinterpret_cast<const bf16x8*>(Wneigh + (size_t)(ot * 16 + m16) * F + ko);
            o = __builtin_amdgcn_mfma_f32_16x16x32_bf16(axs, bs, o, 0, 0, 0);
            o = __builtin_amdgcn_mfma_f32_16x16x32_bf16(am,  bn, o, 0, 0, 0);
        }
        int ocol = ot * 16 + m16;
        float bias = bout[ocol];
        #pragma unroll
        for (int r = 0; r < 4; ++r) {
            int node = s_node[rt * 16 + q * 4 + r];
            float v = o[r] + bias;
            if (RELU) v = fmaxf(v, 0.0f);
            outp[(size_t)node * OUTF + ocol] = (OutT)v;
        }
    }
}

extern "C" void kernel_launch(void* const* d_in, const int* in_sizes, int n_in,
                              void* d_out, int out_size, void* d_ws, size_t ws_size,
                              hipStream_t stream)
{
    const float* feat    = (const float*)d_in[0];
    const int*   nbr     = (const int*)d_in[1];
    const int*   degp    = (const int*)d_in[2];
    const float* Wih1    = (const float*)d_in[3];
    const float* Whh1    = (const float*)d_in[4];
    const float* bih1    = (const float*)d_in[5];
    const float* bhh1    = (const float*)d_in[6];
    const float* Wself1  = (const float*)d_in[7];
    const float* Wneigh1 = (const float*)d_in[8];
    const float* b1      = (const float*)d_in[9];
    const float* Wih2    = (const float*)d_in[10];
    const float* Whh2    = (const float*)d_in[11];
    const float* bih2    = (const float*)d_in[12];
    const float* bhh2    = (const float*)d_in[13];
    const float* Wself2  = (const float*)d_in[14];
    const float* Wneigh2 = (const float*)d_in[15];
    const float* b2      = (const float*)d_in[16];

    bf16_t *hglob, *wglob, *xg1, *xg2;
    int *permg;
    hipGetSymbolAddress((void**)&hglob, HIP_SYMBOL(g_hbuf));
    hipGetSymbolAddress((void**)&wglob, HIP_SYMBOL(g_wbuf));
    hipGetSymbolAddress((void**)&xg1,   HIP_SYMBOL(g_xg1));
    hipGetSymbolAddress((void**)&xg2,   HIP_SYMBOL(g_xg2));
    hipGetSymbolAddress((void**)&permg, HIP_SYMBOL(g_perm));

    cvt_weights<<<W_TOTAL / 4 / 256, 256, 0, stream>>>(
        Wih1, Whh1, Wself1, Wneigh1, Wih2, Whh2, Wself2, Wneigh2);

    build_perm<<<1, 256, 0, stream>>>(degp, permg);

    const int grid = (NN + 63) / 64;   // 469 WGs

    xg_gemm<128, 512, 8, true><<<grid, 512, 0, stream>>>(
        feat, wglob + OFF_WIH1, bih1, bhh1, xg1);

    sage_rec<128, 8, 256, true, true, bf16_t><<<grid, 512, 0, stream>>>(
        feat, xg1, nbr, degp, permg, wglob + OFF_WHH1,
        wglob + OFF_WSELF1, wglob + OFF_WNEIGH1, b1, hglob);

    xg_gemm<256, 1024, 8, false><<<grid, 512, 0, stream>>>(
        hglob, wglob + OFF_WIH2, bih2, bhh2, xg2);

    sage_rec<256, 8, 64, false, false, float><<<grid, 512, 0, stream>>>(
        hglob, xg2, nbr, degp, permg, wglob + OFF_WHH2,
        wglob + OFF_WSELF2, wglob + OFF_WNEIGH2, b2, (float*)d_out);
}